// Round 1
// baseline (899.945 us; speedup 1.0000x reference)
//
#include <hip/hip_runtime.h>
#include <hip/hip_bf16.h>
#include <math.h>

// Problem constants (match reference)
#define BB   1024
#define MM   16
#define KK   32
#define LL   50
#define EE   64

__device__ __forceinline__ float sigf(float x) { return 1.0f / (1.0f + __expf(-x)); }
__device__ __forceinline__ float tanh_fast(float x) { return 2.0f / (1.0f + __expf(-2.0f * x)) - 1.0f; }

// ---------------------------------------------------------------------------
// Kernel A: batched LSTM over 16384 sequences, 50 steps, E=64, gates=256.
// 256 blocks x 256 threads; each block owns 64 sequences (1 block/CU).
// LDS: W_ih^T + W_hh^T (128 KB) + one [k][seq] buffer (16 KB, time-shared
// between h_{t-1} and gathered x_t) + act_seqs indices (12.8 KB) = 160,256 B.
// Thread tile: 4 seqs x 4 e x 4 gates = 64 f32 accumulators.
// ---------------------------------------------------------------------------
__global__ __launch_bounds__(256, 1)
void lstm_kernel(const int* __restrict__ act_seqs, const float* __restrict__ act_table,
                 const float* __restrict__ W_ih, const float* __restrict__ W_hh,
                 const float* __restrict__ b_ih, const float* __restrict__ b_hh,
                 float* __restrict__ m_act)
{
    __shared__ float sW[2][64][256];   // [mtx][k][j]  (j = gate*64 + e), 128 KB
    __shared__ float sBuf[64][64];     // [k][seq] for h-part OR x-part, 16 KB
    __shared__ int   sIdx[64 * 50];    // this block's act_seqs, 12.8 KB

    const int t   = threadIdx.x;
    const int blk = blockIdx.x;        // 0..255, 64 seqs per block
    const int tx  = t & 15;            // e-tile index
    const int ty  = t >> 4;            // seq-tile index
    const int tx4 = tx * 4;
    const int ty4 = ty * 4;

    // --- load W_ih, W_hh transposed into LDS (coalesced: 16 lanes x float4 per row)
    {
        const int kq = (t & 15) * 4;
        const int jr = t >> 4;
        for (int mtx = 0; mtx < 2; ++mtx) {
            const float* W = mtx ? W_hh : W_ih;
            for (int rep = 0; rep < 16; ++rep) {
                int j = rep * 16 + jr;           // gate-row 0..255
                float4 v = *reinterpret_cast<const float4*>(&W[j * 64 + kq]);
                sW[mtx][kq + 0][j] = v.x;
                sW[mtx][kq + 1][j] = v.y;
                sW[mtx][kq + 2][j] = v.z;
                sW[mtx][kq + 3][j] = v.w;
            }
        }
    }
    // --- preload this block's indices (fully coalesced: contiguous 3200 ints)
    {
        const int base = blk * (64 * LL);
        for (int i = t; i < 64 * LL; i += 256) sIdx[i] = act_seqs[base + i];
    }

    // --- bias (b_ih + b_hh), per-thread slice
    float bias[4][4];   // [gate][i]
    #pragma unroll
    for (int g = 0; g < 4; ++g)
        #pragma unroll
        for (int i = 0; i < 4; ++i) {
            int j = g * 64 + tx4 + i;
            bias[g][i] = b_ih[j] + b_hh[j];
        }

    float h[4][4];  // [s][i]
    float c[4][4];
    #pragma unroll
    for (int s = 0; s < 4; ++s)
        #pragma unroll
        for (int i = 0; i < 4; ++i) { h[s][i] = 0.0f; c[s][i] = 0.0f; }

    const int gs = t >> 2;   // gather: sequence row 0..63
    const int gp = t & 3;    // gather: which 16-float chunk of the 64-float row

    for (int step = 0; step < LL; ++step) {
        __syncthreads();   // (A) prev iteration's x-part reads done; W/idx loads visible at step 0

        // write h_{t-1} into sBuf[k=e][seq]
        #pragma unroll
        for (int i = 0; i < 4; ++i)
            #pragma unroll
            for (int s = 0; s < 4; ++s)
                sBuf[tx4 + i][ty4 + s] = h[s][i];
        __syncthreads();   // (B)

        float acc[4][4][4];   // [gate][i][s]
        #pragma unroll
        for (int g = 0; g < 4; ++g)
            #pragma unroll
            for (int i = 0; i < 4; ++i)
                #pragma unroll
                for (int s = 0; s < 4; ++s)
                    acc[g][i][s] = bias[g][i];

        // ----- h-part: acc += h @ W_hh^T
        for (int k = 0; k < 64; ++k) {
            float hv[4];
            *reinterpret_cast<float4*>(hv) = *reinterpret_cast<const float4*>(&sBuf[k][ty4]);
            #pragma unroll
            for (int g = 0; g < 4; ++g) {
                float wv[4];
                *reinterpret_cast<float4*>(wv) = *reinterpret_cast<const float4*>(&sW[1][k][g * 64 + tx4]);
                #pragma unroll
                for (int i = 0; i < 4; ++i)
                    #pragma unroll
                    for (int s = 0; s < 4; ++s)
                        acc[g][i][s] = fmaf(wv[i], hv[s], acc[g][i][s]);
            }
        }
        __syncthreads();   // (C) h reads done, safe to overwrite sBuf

        // ----- gather x_t = act_table[act_seqs[seq, step]] into sBuf[k][seq]
        {
            int id = sIdx[gs * LL + step];
            const float4* src = reinterpret_cast<const float4*>(&act_table[(size_t)id * EE + gp * 16]);
            float4 v0 = src[0], v1 = src[1], v2 = src[2], v3 = src[3];
            int kb = gp * 16;
            sBuf[kb +  0][gs] = v0.x; sBuf[kb +  1][gs] = v0.y; sBuf[kb +  2][gs] = v0.z; sBuf[kb +  3][gs] = v0.w;
            sBuf[kb +  4][gs] = v1.x; sBuf[kb +  5][gs] = v1.y; sBuf[kb +  6][gs] = v1.z; sBuf[kb +  7][gs] = v1.w;
            sBuf[kb +  8][gs] = v2.x; sBuf[kb +  9][gs] = v2.y; sBuf[kb + 10][gs] = v2.z; sBuf[kb + 11][gs] = v2.w;
            sBuf[kb + 12][gs] = v3.x; sBuf[kb + 13][gs] = v3.y; sBuf[kb + 14][gs] = v3.z; sBuf[kb + 15][gs] = v3.w;
        }
        __syncthreads();   // (D)

        // ----- x-part: acc += x @ W_ih^T
        for (int k = 0; k < 64; ++k) {
            float xv[4];
            *reinterpret_cast<float4*>(xv) = *reinterpret_cast<const float4*>(&sBuf[k][ty4]);
            #pragma unroll
            for (int g = 0; g < 4; ++g) {
                float wv[4];
                *reinterpret_cast<float4*>(wv) = *reinterpret_cast<const float4*>(&sW[0][k][g * 64 + tx4]);
                #pragma unroll
                for (int i = 0; i < 4; ++i)
                    #pragma unroll
                    for (int s = 0; s < 4; ++s)
                        acc[g][i][s] = fmaf(wv[i], xv[s], acc[g][i][s]);
            }
        }

        // ----- gate nonlinearities (PyTorch order i,f,g,o)
        #pragma unroll
        for (int s = 0; s < 4; ++s)
            #pragma unroll
            for (int i = 0; i < 4; ++i) {
                float ig = acc[0][i][s];
                float fg = acc[1][i][s];
                float gg = acc[2][i][s];
                float og = acc[3][i][s];
                float cc = sigf(fg) * c[s][i] + sigf(ig) * tanh_fast(gg);
                c[s][i] = cc;
                h[s][i] = sigf(og) * tanh_fast(cc);
            }
    }

    // write final h -> m_act [16384][64]
    #pragma unroll
    for (int s = 0; s < 4; ++s) {
        float4 v = make_float4(h[s][0], h[s][1], h[s][2], h[s][3]);
        *reinterpret_cast<float4*>(&m_act[((size_t)(blk * 64 + ty4 + s)) * EE + tx4]) = v;
    }
}

// ---------------------------------------------------------------------------
// Kernel B: GCN gather + linear/relu + fuse + PNA reduce + MLPs + predict.
// One block per batch element b (1024 blocks x 256 threads).
// ---------------------------------------------------------------------------
__global__ __launch_bounds__(256)
void post_kernel(const int* __restrict__ members, const int* __restrict__ neighbors,
                 const int* __restrict__ act_inputs,
                 const float* __restrict__ act_table, const float* __restrict__ user_table,
                 const float* __restrict__ gcn_W, const float* __restrict__ gcn_b,
                 const float* __restrict__ pna_W1, const float* __restrict__ pna_b1,
                 const float* __restrict__ pna_W2, const float* __restrict__ pna_b2,
                 const float* __restrict__ pna_W3, const float* __restrict__ pna_b3,
                 const float* __restrict__ pred_W1, const float* __restrict__ pred_b1,
                 const float* __restrict__ pred_W2, const float* __restrict__ pred_b2,
                 const float* __restrict__ m_act, float* __restrict__ out)
{
    __shared__ float sWg[64][64];    // gcn_W transposed [k][e]
    __shared__ float sAgg[16][64];
    __shared__ float sFus[16][64];
    __shared__ float sActe[64];
    __shared__ float sFeats[256];
    __shared__ float sPart[4][64];
    __shared__ float sH1[64];
    __shared__ float sH2[64];
    __shared__ float sGrp[64];
    __shared__ float sHH[8];

    const int t  = threadIdx.x;
    const int b  = blockIdx.x;
    const int e  = t & 63;
    const int mq = t >> 6;   // 0..3 (wave id)

    // transpose gcn_W into LDS (gcn_W[e][k] -> sWg[k][e]) so GEMM reads are conflict-free
    {
        const int kq = (t & 15) * 4;
        const int er = t >> 4;   // 0..15
        #pragma unroll
        for (int rep = 0; rep < 4; ++rep) {
            int row = rep * 16 + er;
            float4 v = *reinterpret_cast<const float4*>(&gcn_W[row * 64 + kq]);
            sWg[kq + 0][row] = v.x;
            sWg[kq + 1][row] = v.y;
            sWg[kq + 2][row] = v.z;
            sWg[kq + 3][row] = v.w;
        }
    }
    if (t < 64) sActe[t] = act_table[(size_t)act_inputs[b] * EE + t];

    // neighborhood aggregation: (member + sum(neighbors)) / (K+1)
    for (int mb = 0; mb < 4; ++mb) {
        int m = mb * 4 + mq;
        int base = b * MM + m;
        float s_ = user_table[(size_t)members[base] * EE + e];
        const int* nb = &neighbors[base * KK];
        #pragma unroll 4
        for (int kk = 0; kk < KK; ++kk)
            s_ += user_table[(size_t)nb[kk] * EE + e];
        sAgg[m][e] = s_ * (1.0f / 33.0f);
    }
    __syncthreads();

    // m_gcn = relu(agg @ gcn_W^T + b); fus = m_act + m_gcn
    for (int mb = 0; mb < 4; ++mb) {
        int m = mb * 4 + mq;
        float a = gcn_b[e];
        #pragma unroll
        for (int k = 0; k < 64; ++k) a = fmaf(sAgg[m][k], sWg[k][e], a);
        a = fmaxf(a, 0.0f);
        sFus[m][e] = m_act[((size_t)(b * MM + m)) * EE + e] + a;
    }
    __syncthreads();

    // PNA reduce over M: amp = log(M+1)/log(AVG_M+1) = 1.0 exactly (M == AVG_M == 16)
    if (t < 64) {
        float mn = 0.0f, mx = -INFINITY;
        #pragma unroll
        for (int m = 0; m < MM; ++m) { float v = sFus[m][t]; mn += v; mx = fmaxf(mx, v); }
        mn *= (1.0f / 16.0f);
        sFeats[t] = mn; sFeats[64 + t] = mx; sFeats[128 + t] = mn; sFeats[192 + t] = mx;
    }
    __syncthreads();

    // h1 = relu(feats @ pna_W1 + b1): 256 -> 64, split k over 4 waves
    {
        float p = 0.0f;
        #pragma unroll 8
        for (int kk = 0; kk < 64; ++kk) {
            int k = mq * 64 + kk;
            p = fmaf(sFeats[k], pna_W1[(size_t)k * 64 + e], p);
        }
        sPart[mq][e] = p;
    }
    __syncthreads();
    if (t < 64) sH1[t] = fmaxf(pna_b1[t] + sPart[0][t] + sPart[1][t] + sPart[2][t] + sPart[3][t], 0.0f);
    __syncthreads();

    // h2 = relu(h1 @ pna_W2 + b2): 64 -> 64
    {
        float p = 0.0f;
        #pragma unroll
        for (int kk = 0; kk < 16; ++kk) {
            int k = mq * 16 + kk;
            p = fmaf(sH1[k], pna_W2[(size_t)k * 64 + e], p);
        }
        sPart[mq][e] = p;
    }
    __syncthreads();
    if (t < 64) sH2[t] = fmaxf(pna_b2[t] + sPart[0][t] + sPart[1][t] + sPart[2][t] + sPart[3][t], 0.0f);
    __syncthreads();

    // grp = h2 @ pna_W3 + b3
    {
        float p = 0.0f;
        #pragma unroll
        for (int kk = 0; kk < 16; ++kk) {
            int k = mq * 16 + kk;
            p = fmaf(sH2[k], pna_W3[(size_t)k * 64 + e], p);
        }
        sPart[mq][e] = p;
    }
    __syncthreads();
    if (t < 64) sGrp[t] = pna_b3[t] + sPart[0][t] + sPart[1][t] + sPart[2][t] + sPart[3][t];
    __syncthreads();

    // predict: cat = [grp*act_e, grp, act_e]; hh = relu(cat @ pred_W1 + b1); y = sigmoid(hh @ pred_W2 + b2)
    if (t < 8) {
        float a = pred_b1[t];
        for (int k = 0; k < 192; ++k) {
            float cv = (k < 64) ? sGrp[k] * sActe[k]
                                : ((k < 128) ? sGrp[k - 64] : sActe[k - 128]);
            a = fmaf(cv, pred_W1[k * 8 + t], a);
        }
        sHH[t] = fmaxf(a, 0.0f);
    }
    __syncthreads();
    if (t == 0) {
        float y = pred_b2[0];
        #pragma unroll
        for (int j = 0; j < 8; ++j) y = fmaf(sHH[j], pred_W2[j], y);
        out[b] = 1.0f / (1.0f + expf(-y));
    }
}

extern "C" void kernel_launch(void* const* d_in, const int* in_sizes, int n_in,
                              void* d_out, int out_size, void* d_ws, size_t ws_size,
                              hipStream_t stream) {
    const int*   members    = (const int*)d_in[0];
    const int*   neighbors  = (const int*)d_in[1];
    const int*   act_inputs = (const int*)d_in[2];
    const int*   act_seqs   = (const int*)d_in[3];
    const float* act_table  = (const float*)d_in[4];
    const float* user_table = (const float*)d_in[5];
    const float* W_ih       = (const float*)d_in[6];
    const float* W_hh       = (const float*)d_in[7];
    const float* b_ih       = (const float*)d_in[8];
    const float* b_hh       = (const float*)d_in[9];
    const float* gcn_W      = (const float*)d_in[10];
    const float* gcn_b      = (const float*)d_in[11];
    const float* pna_W1     = (const float*)d_in[12];
    const float* pna_b1     = (const float*)d_in[13];
    const float* pna_W2     = (const float*)d_in[14];
    const float* pna_b2     = (const float*)d_in[15];
    const float* pna_W3     = (const float*)d_in[16];
    const float* pna_b3     = (const float*)d_in[17];
    const float* pred_W1    = (const float*)d_in[18];
    const float* pred_b1    = (const float*)d_in[19];
    const float* pred_W2    = (const float*)d_in[20];
    const float* pred_b2    = (const float*)d_in[21];

    float* m_act = (float*)d_ws;   // [16384][64] f32 = 4 MB scratch

    lstm_kernel<<<dim3(256), dim3(256), 0, stream>>>(
        act_seqs, act_table, W_ih, W_hh, b_ih, b_hh, m_act);

    post_kernel<<<dim3(BB), dim3(256), 0, stream>>>(
        members, neighbors, act_inputs, act_table, user_table,
        gcn_W, gcn_b, pna_W1, pna_b1, pna_W2, pna_b2, pna_W3, pna_b3,
        pred_W1, pred_b1, pred_W2, pred_b2, m_act, (float*)d_out);
}

// Round 2
// 203.429 us; speedup vs baseline: 4.4239x; 4.4239x over previous
//
#include <hip/hip_runtime.h>
#include <hip/hip_bf16.h>
#include <math.h>

// Problem constants (match reference)
#define BB   1024
#define MM   16
#define KK   32
#define LL   50
#define EE   64

typedef __attribute__((ext_vector_type(8))) short short8;
typedef float v4f __attribute__((ext_vector_type(4)));

__device__ __forceinline__ float sigf(float x) { return 1.0f / (1.0f + __expf(-x)); }
__device__ __forceinline__ float tanh_fast(float x) { return 2.0f / (1.0f + __expf(-2.0f * x)) - 1.0f; }

__device__ __forceinline__ short f2bf(float f) {
    unsigned u = __builtin_bit_cast(unsigned, f);
    u += 0x7FFFu + ((u >> 16) & 1u);   // round-to-nearest-even
    return (short)(u >> 16);
}

// ---------------------------------------------------------------------------
// MFMA LSTM: 512 blocks x 256 threads; 32 sequences/block; 2 blocks/CU.
// Per wave w: gates[32 s][j = g*64 + 16w + c] for g=0..3, c=0..15 -> all 4
// gates of a given (s,e) live in the same lane+reg (nonlinearity is local).
// Weights as register-resident B-frags; x/h stream via swizzled bf16 LDS.
// ---------------------------------------------------------------------------
__global__ __launch_bounds__(256, 2)
void lstm_mfma(const int* __restrict__ act_seqs, const float* __restrict__ act_table,
               const float* __restrict__ W_ih, const float* __restrict__ W_hh,
               const float* __restrict__ b_ih, const float* __restrict__ b_hh,
               float* __restrict__ m_act)
{
    __shared__ __align__(16) short sH[32 * 64];       // h_{t-1}, bf16, swizzled
    __shared__ __align__(16) short sX[2][32 * 64];    // x_t double buffer, bf16, swizzled
    __shared__ int sIdx[32 * LL];

    const int t    = threadIdx.x;
    const int blk  = blockIdx.x;
    const int lane = t & 63;
    const int w    = t >> 6;        // wave id = e-block (0..3)
    const int lr   = lane & 15;     // A-row / B-col / D-col selector
    const int lb   = lane >> 4;     // k-block selector (0..3)

    // --- this block's indices (contiguous 1600 ints, coalesced)
    for (int i = t; i < 32 * LL; i += 256) sIdx[i] = act_seqs[blk * 32 * LL + i];

    // --- weights -> register B-frags. B[k][n]: lane holds n=lr, k=32*ks+8*lb+i.
    // gates = in @ W^T  =>  B[k][j] = W[j][k], row j = g*64 + 16w + lr.
    short8 Bf[2][4][2];   // [mat(ih,hh)][gate][ks]
    #pragma unroll
    for (int mat = 0; mat < 2; ++mat) {
        const float* W = mat ? W_hh : W_ih;
        #pragma unroll
        for (int g = 0; g < 4; ++g) {
            const int j = g * 64 + w * 16 + lr;
            #pragma unroll
            for (int ks = 0; ks < 2; ++ks) {
                const float4* p = reinterpret_cast<const float4*>(&W[(size_t)j * 64 + ks * 32 + lb * 8]);
                float4 v0 = p[0], v1 = p[1];
                short8 f;
                f[0] = f2bf(v0.x); f[1] = f2bf(v0.y); f[2] = f2bf(v0.z); f[3] = f2bf(v0.w);
                f[4] = f2bf(v1.x); f[5] = f2bf(v1.y); f[6] = f2bf(v1.z); f[7] = f2bf(v1.w);
                Bf[mat][g][ks] = f;
            }
        }
    }
    float bias[4];
    #pragma unroll
    for (int g = 0; g < 4; ++g) {
        const int j = g * 64 + w * 16 + lr;
        bias[g] = b_ih[j] + b_hh[j];
    }

    float h[2][4], c[2][4];
    #pragma unroll
    for (int mt = 0; mt < 2; ++mt)
        #pragma unroll
        for (int r = 0; r < 4; ++r) { h[mt][r] = 0.0f; c[mt][r] = 0.0f; }

    __syncthreads();   // sIdx visible

    // --- stage x_0 into sX[0] (swizzled bf16). thread: row xs, 8-float chunk xf.
    const int xs = t >> 3;    // 0..31
    const int xf = t & 7;     // chunk 0..7
    {
        const int id = sIdx[xs * LL + 0];
        const float4* src = reinterpret_cast<const float4*>(&act_table[(size_t)id * EE + xf * 8]);
        float4 v0 = src[0], v1 = src[1];
        short8 f;
        f[0] = f2bf(v0.x); f[1] = f2bf(v0.y); f[2] = f2bf(v0.z); f[3] = f2bf(v0.w);
        f[4] = f2bf(v1.x); f[5] = f2bf(v1.y); f[6] = f2bf(v1.z); f[7] = f2bf(v1.w);
        *reinterpret_cast<short8*>(reinterpret_cast<char*>(sX[0]) + xs * 128 + ((xf ^ (xs & 7)) << 4)) = f;
    }

    for (int step = 0; step < LL; ++step) {
        const int cur = step & 1;

        // 1. prefetch x_{t+1} rows into registers (latency hides under MFMA+nonlin)
        float4 pv0, pv1;
        const bool havePf = (step + 1 < LL);
        if (havePf) {
            const int id = sIdx[xs * LL + step + 1];
            const float4* src = reinterpret_cast<const float4*>(&act_table[(size_t)id * EE + xf * 8]);
            pv0 = src[0]; pv1 = src[1];
        }

        // 2. write h_{t-1} (zeros at step 0) into sH, bf16, swizzled
        #pragma unroll
        for (int mt = 0; mt < 2; ++mt)
            #pragma unroll
            for (int r = 0; r < 4; ++r) {
                const int s = mt * 16 + lb * 4 + r;          // D row
                const int e = w * 16 + lr;                   // D col
                sH[s * 64 + ((((e >> 3) ^ (s & 7)) << 3) | (e & 7))] = f2bf(h[mt][r]);
            }
        __syncthreads();   // (B) h + x buffers ready

        // 3. gates = bias + x @ Wih^T + h @ Whh^T   (MFMA)
        v4f acc[2][4];
        #pragma unroll
        for (int mt = 0; mt < 2; ++mt)
            #pragma unroll
            for (int g = 0; g < 4; ++g) {
                v4f a; a[0] = bias[g]; a[1] = bias[g]; a[2] = bias[g]; a[3] = bias[g];
                acc[mt][g] = a;
            }
        #pragma unroll
        for (int ks = 0; ks < 2; ++ks) {
            #pragma unroll
            for (int mt = 0; mt < 2; ++mt) {
                const int s0 = mt * 16 + lr;                 // A row
                const int cb = 4 * ks + lb;                  // 16B chunk (k = 8*cb..+7)
                const int off = s0 * 128 + (((cb ^ (s0 & 7)) << 4));
                short8 ax = *reinterpret_cast<const short8*>(reinterpret_cast<const char*>(sX[cur]) + off);
                short8 ah = *reinterpret_cast<const short8*>(reinterpret_cast<const char*>(sH) + off);
                #pragma unroll
                for (int g = 0; g < 4; ++g)
                    acc[mt][g] = __builtin_amdgcn_mfma_f32_16x16x32_bf16(ax, Bf[0][g][ks], acc[mt][g], 0, 0, 0);
                #pragma unroll
                for (int g = 0; g < 4; ++g)
                    acc[mt][g] = __builtin_amdgcn_mfma_f32_16x16x32_bf16(ah, Bf[1][g][ks], acc[mt][g], 0, 0, 0);
            }
        }

        // 4. gate nonlinearities (i,f,g,o), register-local
        #pragma unroll
        for (int mt = 0; mt < 2; ++mt)
            #pragma unroll
            for (int r = 0; r < 4; ++r) {
                const float ig = acc[mt][0][r];
                const float fg = acc[mt][1][r];
                const float gg = acc[mt][2][r];
                const float og = acc[mt][3][r];
                const float cc = sigf(fg) * c[mt][r] + sigf(ig) * tanh_fast(gg);
                c[mt][r] = cc;
                h[mt][r] = sigf(og) * tanh_fast(cc);
            }

        // 5. write x_{t+1} into the other buffer (was last read at step t-1)
        if (havePf) {
            short8 f;
            f[0] = f2bf(pv0.x); f[1] = f2bf(pv0.y); f[2] = f2bf(pv0.z); f[3] = f2bf(pv0.w);
            f[4] = f2bf(pv1.x); f[5] = f2bf(pv1.y); f[6] = f2bf(pv1.z); f[7] = f2bf(pv1.w);
            *reinterpret_cast<short8*>(reinterpret_cast<char*>(sX[cur ^ 1]) + xs * 128 + ((xf ^ (xs & 7)) << 4)) = f;
        }
        __syncthreads();   // (A) reads of sH/sX done before next overwrite
    }

    // --- write final h -> m_act [16384][64] f32
    #pragma unroll
    for (int mt = 0; mt < 2; ++mt)
        #pragma unroll
        for (int r = 0; r < 4; ++r) {
            const int s = mt * 16 + lb * 4 + r;
            const int e = w * 16 + lr;
            m_act[((size_t)(blk * 32 + s)) * EE + e] = h[mt][r];
        }
}

// ---------------------------------------------------------------------------
// Kernel B: GCN gather + linear/relu + fuse + PNA reduce + MLPs + predict.
// One block per batch element b (1024 blocks x 256 threads). (unchanged)
// ---------------------------------------------------------------------------
__global__ __launch_bounds__(256)
void post_kernel(const int* __restrict__ members, const int* __restrict__ neighbors,
                 const int* __restrict__ act_inputs,
                 const float* __restrict__ act_table, const float* __restrict__ user_table,
                 const float* __restrict__ gcn_W, const float* __restrict__ gcn_b,
                 const float* __restrict__ pna_W1, const float* __restrict__ pna_b1,
                 const float* __restrict__ pna_W2, const float* __restrict__ pna_b2,
                 const float* __restrict__ pna_W3, const float* __restrict__ pna_b3,
                 const float* __restrict__ pred_W1, const float* __restrict__ pred_b1,
                 const float* __restrict__ pred_W2, const float* __restrict__ pred_b2,
                 const float* __restrict__ m_act, float* __restrict__ out)
{
    __shared__ float sWg[64][64];    // gcn_W transposed [k][e]
    __shared__ float sAgg[16][64];
    __shared__ float sFus[16][64];
    __shared__ float sActe[64];
    __shared__ float sFeats[256];
    __shared__ float sPart[4][64];
    __shared__ float sH1[64];
    __shared__ float sH2[64];
    __shared__ float sGrp[64];
    __shared__ float sHH[8];

    const int t  = threadIdx.x;
    const int b  = blockIdx.x;
    const int e  = t & 63;
    const int mq = t >> 6;   // 0..3 (wave id)

    {
        const int kq = (t & 15) * 4;
        const int er = t >> 4;   // 0..15
        #pragma unroll
        for (int rep = 0; rep < 4; ++rep) {
            int row = rep * 16 + er;
            float4 v = *reinterpret_cast<const float4*>(&gcn_W[row * 64 + kq]);
            sWg[kq + 0][row] = v.x;
            sWg[kq + 1][row] = v.y;
            sWg[kq + 2][row] = v.z;
            sWg[kq + 3][row] = v.w;
        }
    }
    if (t < 64) sActe[t] = act_table[(size_t)act_inputs[b] * EE + t];

    for (int mb = 0; mb < 4; ++mb) {
        int m = mb * 4 + mq;
        int base = b * MM + m;
        float s_ = user_table[(size_t)members[base] * EE + e];
        const int* nb = &neighbors[base * KK];
        #pragma unroll 4
        for (int kk = 0; kk < KK; ++kk)
            s_ += user_table[(size_t)nb[kk] * EE + e];
        sAgg[m][e] = s_ * (1.0f / 33.0f);
    }
    __syncthreads();

    for (int mb = 0; mb < 4; ++mb) {
        int m = mb * 4 + mq;
        float a = gcn_b[e];
        #pragma unroll
        for (int k = 0; k < 64; ++k) a = fmaf(sAgg[m][k], sWg[k][e], a);
        a = fmaxf(a, 0.0f);
        sFus[m][e] = m_act[((size_t)(b * MM + m)) * EE + e] + a;
    }
    __syncthreads();

    if (t < 64) {
        float mn = 0.0f, mx = -INFINITY;
        #pragma unroll
        for (int m = 0; m < MM; ++m) { float v = sFus[m][t]; mn += v; mx = fmaxf(mx, v); }
        mn *= (1.0f / 16.0f);
        sFeats[t] = mn; sFeats[64 + t] = mx; sFeats[128 + t] = mn; sFeats[192 + t] = mx;
    }
    __syncthreads();

    {
        float p = 0.0f;
        #pragma unroll 8
        for (int kk = 0; kk < 64; ++kk) {
            int k = mq * 64 + kk;
            p = fmaf(sFeats[k], pna_W1[(size_t)k * 64 + e], p);
        }
        sPart[mq][e] = p;
    }
    __syncthreads();
    if (t < 64) sH1[t] = fmaxf(pna_b1[t] + sPart[0][t] + sPart[1][t] + sPart[2][t] + sPart[3][t], 0.0f);
    __syncthreads();

    {
        float p = 0.0f;
        #pragma unroll
        for (int kk = 0; kk < 16; ++kk) {
            int k = mq * 16 + kk;
            p = fmaf(sH1[k], pna_W2[(size_t)k * 64 + e], p);
        }
        sPart[mq][e] = p;
    }
    __syncthreads();
    if (t < 64) sH2[t] = fmaxf(pna_b2[t] + sPart[0][t] + sPart[1][t] + sPart[2][t] + sPart[3][t], 0.0f);
    __syncthreads();

    {
        float p = 0.0f;
        #pragma unroll
        for (int kk = 0; kk < 16; ++kk) {
            int k = mq * 16 + kk;
            p = fmaf(sH2[k], pna_W3[(size_t)k * 64 + e], p);
        }
        sPart[mq][e] = p;
    }
    __syncthreads();
    if (t < 64) sGrp[t] = pna_b3[t] + sPart[0][t] + sPart[1][t] + sPart[2][t] + sPart[3][t];
    __syncthreads();

    if (t < 8) {
        float a = pred_b1[t];
        for (int k = 0; k < 192; ++k) {
            float cv = (k < 64) ? sGrp[k] * sActe[k]
                                : ((k < 128) ? sGrp[k - 64] : sActe[k - 128]);
            a = fmaf(cv, pred_W1[k * 8 + t], a);
        }
        sHH[t] = fmaxf(a, 0.0f);
    }
    __syncthreads();
    if (t == 0) {
        float y = pred_b2[0];
        #pragma unroll
        for (int j = 0; j < 8; ++j) y = fmaf(sHH[j], pred_W2[j], y);
        out[b] = 1.0f / (1.0f + expf(-y));
    }
}

extern "C" void kernel_launch(void* const* d_in, const int* in_sizes, int n_in,
                              void* d_out, int out_size, void* d_ws, size_t ws_size,
                              hipStream_t stream) {
    const int*   members    = (const int*)d_in[0];
    const int*   neighbors  = (const int*)d_in[1];
    const int*   act_inputs = (const int*)d_in[2];
    const int*   act_seqs   = (const int*)d_in[3];
    const float* act_table  = (const float*)d_in[4];
    const float* user_table = (const float*)d_in[5];
    const float* W_ih       = (const float*)d_in[6];
    const float* W_hh       = (const float*)d_in[7];
    const float* b_ih       = (const float*)d_in[8];
    const float* b_hh       = (const float*)d_in[9];
    const float* gcn_W      = (const float*)d_in[10];
    const float* gcn_b      = (const float*)d_in[11];
    const float* pna_W1     = (const float*)d_in[12];
    const float* pna_b1     = (const float*)d_in[13];
    const float* pna_W2     = (const float*)d_in[14];
    const float* pna_b2     = (const float*)d_in[15];
    const float* pna_W3     = (const float*)d_in[16];
    const float* pna_b3     = (const float*)d_in[17];
    const float* pred_W1    = (const float*)d_in[18];
    const float* pred_b1    = (const float*)d_in[19];
    const float* pred_W2    = (const float*)d_in[20];
    const float* pred_b2    = (const float*)d_in[21];

    float* m_act = (float*)d_ws;   // [16384][64] f32 = 4 MB scratch

    lstm_mfma<<<dim3(512), dim3(256), 0, stream>>>(
        act_seqs, act_table, W_ih, W_hh, b_ih, b_hh, m_act);

    post_kernel<<<dim3(BB), dim3(256), 0, stream>>>(
        members, neighbors, act_inputs, act_table, user_table,
        gcn_W, gcn_b, pna_W1, pna_b1, pna_W2, pna_b2, pna_W3, pna_b3,
        pred_W1, pred_b1, pred_W2, pred_b2, m_act, (float*)d_out);
}